// Round 12
// baseline (125.207 us; speedup 1.0000x reference)
//
#include <hip/hip_runtime.h>
#include <math.h>

#define BB 32
#define TT 2048
#define DD 1024   // HID == OUT == DV == 1024
#define HF 512    // OUT/2

#define QKS 64            // k-split chunks for query projection
#define QCH (DD / QKS)    // 16 h per chunk

#define CHK 32            // t-rows per fused score+context chunk
#define NCH (TT / CHK)    // 64 chunks per batch row

#define KSC 2.88539008177792681f   // 2*log2(e): exp(2x) == exp2(KSC*x)

#if __has_builtin(__builtin_amdgcn_exp2f)
#define EXP2F(x) __builtin_amdgcn_exp2f(x)
#else
#define EXP2F(x) exp2f(x)
#endif

// ---------------------------------------------------------------------------
// blocks 0..3: w[d]=sum_j W1[d,j]*W2[j]; block 4: cbias; blocks 5..260: qpart
__global__ void __launch_bounds__(256) prep_query_kernel(
        const float* __restrict__ hidden, const float* __restrict__ Wq,
        const float* __restrict__ W1, const float* __restrict__ b1,
        const float* __restrict__ W2, const float* __restrict__ b2,
        float* __restrict__ w, float* __restrict__ cbias,
        float* __restrict__ qpart) {
    __shared__ float smem[BB * QCH];   // 512 floats
    int bx  = blockIdx.x;
    int tid = threadIdx.x;

    if (bx < 4) {                                   // ---- w = W1 @ W2
        int d = bx * 256 + tid;
        const float* row = W1 + (size_t)d * HF;
        float acc = 0.0f;
        #pragma unroll 8
        for (int j = 0; j < HF; j += 4) {
            float4 a = *(const float4*)(row + j);
            float4 b = *(const float4*)(W2 + j);
            acc += a.x * b.x + a.y * b.y + a.z * b.z + a.w * b.w;
        }
        w[d] = acc;
        return;
    }
    if (bx == 4) {                                  // ---- cbias
        __shared__ float red[256];
        float s = b1[tid] * W2[tid] + b1[tid + 256] * W2[tid + 256];
        red[tid] = s;
        __syncthreads();
        for (int off = 128; off; off >>= 1) {
            if (tid < off) red[tid] += red[tid + off];
            __syncthreads();
        }
        if (tid == 0) cbias[0] = red[0] + b2[0];
        return;
    }
    // ---- query partial: idx -> (otile, ks)
    int idx = bx - 5, otile = idx & 3, ks = idx >> 2;
    int o = otile * 256 + tid, h0 = ks * QCH;
    if (tid < 128) {   // 128 threads x float4 = 512 floats = 32 rows x 16 h
        int r = tid >> 2, c4 = (tid & 3) << 2;
        *(float4*)&smem[r * QCH + c4] = *(const float4*)&hidden[(size_t)r * DD + h0 + c4];
    }
    __syncthreads();

    float wv[QCH];
    #pragma unroll
    for (int h = 0; h < QCH; ++h)
        wv[h] = Wq[(size_t)(h0 + h) * DD + o];

    float acc[BB];
    #pragma unroll
    for (int b = 0; b < BB; ++b) acc[b] = 0.0f;
    #pragma unroll
    for (int h = 0; h < QCH; ++h) {
        #pragma unroll
        for (int b = 0; b < BB; ++b)
            acc[b] = fmaf(smem[b * QCH + h], wv[h], acc[b]);
    }
    #pragma unroll
    for (int b = 0; b < BB; ++b)
        qpart[((size_t)ks * BB + b) * DD + o] = acc[b];
}

// ---------------------------------------------------------------------------
// blocks 0..255: query[b,o] = bq[o] + sum_ks qpart[ks][b][o]
// block 256    : cb[1] = cb[0] + sum_d w[d]   (bias for the sigma-form score)
__global__ void __launch_bounds__(256) qreduce_kernel(
        const float* __restrict__ qpart, const float* __restrict__ bq,
        const float* __restrict__ w, float* __restrict__ cb,
        float* __restrict__ query) {
    __shared__ float part[256];
    int bx = blockIdx.x, tid = threadIdx.x;
    if (bx == 256) {                                // ---- Wsum role
        float s = w[tid] + w[tid + 256] + w[tid + 512] + w[tid + 768];
        part[tid] = s;
        __syncthreads();
        for (int off = 128; off; off >>= 1) {
            if (tid < off) part[tid] += part[tid + off];
            __syncthreads();
        }
        if (tid == 0) cb[1] = cb[0] + part[0];
        return;
    }
    int e = tid & 127, g = tid >> 7;
    int i = bx * 128 + e;
    int ks0 = g * (QKS / 2);
    float a0 = 0.0f, a1 = 0.0f, a2 = 0.0f, a3 = 0.0f;
    #pragma unroll 8
    for (int k = 0; k < QKS / 2; k += 4) {
        size_t base = (size_t)(ks0 + k) * (BB * DD) + i;
        a0 += qpart[base];
        a1 += qpart[base + (size_t)(BB * DD)];
        a2 += qpart[base + 2 * (size_t)(BB * DD)];
        a3 += qpart[base + 3 * (size_t)(BB * DD)];
    }
    part[tid] = (a0 + a1) + (a2 + a3);
    __syncthreads();
    if (g == 0) query[i] = bq[i & (DD - 1)] + part[tid] + part[tid + 128];
}

// ---------------------------------------------------------------------------
// Fused score+PV, barrier-free interleaved stream. Each wave owns rows
// j*4+wave end-to-end: prefetch key row j+1 (2-deep, 8-iter proven unroll),
// issue value row j loads (independent of e), sigma-form score, 64-lane
// butterfly (e wave-uniform), FMA into per-wave acc[4]. One barrier at end;
// LDS-reduce 4 per-wave accumulators (fixed order). Residency decode as R11.
__global__ void __launch_bounds__(256, 5) score_ctx_kernel(
        const float* __restrict__ key, const float* __restrict__ value,
        const float* __restrict__ query, const float* __restrict__ w,
        const float* __restrict__ cb, const int* __restrict__ seq_lens,
        float* __restrict__ escore, float* __restrict__ psum,
        float* __restrict__ partial) {
    int n    = blockIdx.x;                    // 0..2047
    int hi   = n >> 8;                        // 3 bits
    int b    = (((n & 7) ^ hi) << 2) | ((n >> 6) & 3);
    int x    = ((n >> 3) & 7) | (hi << 3);
    int len  = seq_lens[b];
    int t0   = x * CHK;
    if (t0 >= len) return;

    __shared__ float wsh[DD];
    __shared__ float qsh[DD];
    __shared__ float redbuf[4][DD];           // 16 KB per-wave partials
    __shared__ float esums[4];
    int tid = threadIdx.x;
    { int i4 = tid * 4;
      float4 w4 = *(const float4*)&w[i4];
      float4 q4 = *(const float4*)&query[(size_t)b * DD + i4];
      float4 ws = {-2.0f * w4.x, -2.0f * w4.y, -2.0f * w4.z, -2.0f * w4.w};
      float4 qs = {KSC * q4.x, KSC * q4.y, KSC * q4.z, KSC * q4.w};
      *(float4*)&wsh[i4] = ws;
      *(float4*)&qsh[i4] = qs; }
    __syncthreads();

    int wave = tid >> 6, lane = tid & 63, l4 = lane * 4;
    float c2 = cb[1];                 // cbias + sum_d w
    const float* kb0 = key   + (size_t)b * TT * DD;
    const float* vb0 = value + (size_t)b * TT * DD;

    float4 acc[4];
    #pragma unroll
    for (int s = 0; s < 4; ++s) acc[s] = make_float4(0.f, 0.f, 0.f, 0.f);
    float esum = 0.0f;

    float4 kreg[2][4];
    {
        const float* kr = kb0 + (size_t)(t0 + wave) * DD;
        #pragma unroll
        for (int s = 0; s < 4; ++s)
            kreg[0][s] = *(const float4*)(kr + s * 256 + l4);
    }

    #pragma unroll
    for (int j = 0; j < 8; ++j) {
        int t = t0 + j * 4 + wave;
        if (j < 7) {                          // prefetch next key row
            const float* kr = kb0 + (size_t)(t + 4) * DD;
            #pragma unroll
            for (int s = 0; s < 4; ++s)
                kreg[(j + 1) & 1][s] = *(const float4*)(kr + s * 256 + l4);
        }
        // value row loads (independent of e) — issue before the reduce chain
        const float* vr = vb0 + (size_t)t * DD;
        float4 v0 = *(const float4*)(vr + l4);
        float4 v1 = *(const float4*)(vr + 256 + l4);
        float4 v2 = *(const float4*)(vr + 512 + l4);
        float4 v3 = *(const float4*)(vr + 768 + l4);

        float sa = 0.0f;
        #pragma unroll
        for (int s = 0; s < 4; ++s) {
            int d = s * 256 + l4;
            float4 kv = kreg[j & 1][s];
            float4 qv = *(const float4*)&qsh[d];
            float4 wv = *(const float4*)&wsh[d];
            float r0 = __builtin_amdgcn_rcpf(EXP2F(fmaf(kv.x, KSC, qv.x)) + 1.0f);
            float r1 = __builtin_amdgcn_rcpf(EXP2F(fmaf(kv.y, KSC, qv.y)) + 1.0f);
            float r2 = __builtin_amdgcn_rcpf(EXP2F(fmaf(kv.z, KSC, qv.z)) + 1.0f);
            float r3 = __builtin_amdgcn_rcpf(EXP2F(fmaf(kv.w, KSC, qv.w)) + 1.0f);
            sa = fmaf(wv.x, r0, sa);
            sa = fmaf(wv.y, r1, sa);
            sa = fmaf(wv.z, r2, sa);
            sa = fmaf(wv.w, r3, sa);
        }
        #pragma unroll
        for (int m = 1; m < 64; m <<= 1) sa += __shfl_xor(sa, m);

        float e = (t < len) ? __expf(sa + c2) : 0.0f;   // wave-uniform
        esum += e;
        if (lane == 0) escore[(size_t)b * TT + t] = e;

        acc[0].x = fmaf(e, v0.x, acc[0].x); acc[0].y = fmaf(e, v0.y, acc[0].y);
        acc[0].z = fmaf(e, v0.z, acc[0].z); acc[0].w = fmaf(e, v0.w, acc[0].w);
        acc[1].x = fmaf(e, v1.x, acc[1].x); acc[1].y = fmaf(e, v1.y, acc[1].y);
        acc[1].z = fmaf(e, v1.z, acc[1].z); acc[1].w = fmaf(e, v1.w, acc[1].w);
        acc[2].x = fmaf(e, v2.x, acc[2].x); acc[2].y = fmaf(e, v2.y, acc[2].y);
        acc[2].z = fmaf(e, v2.z, acc[2].z); acc[2].w = fmaf(e, v2.w, acc[2].w);
        acc[3].x = fmaf(e, v3.x, acc[3].x); acc[3].y = fmaf(e, v3.y, acc[3].y);
        acc[3].z = fmaf(e, v3.z, acc[3].z); acc[3].w = fmaf(e, v3.w, acc[3].w);
    }

    if (lane == 0) esums[wave] = esum;
    #pragma unroll
    for (int s = 0; s < 4; ++s)
        *(float4*)&redbuf[wave][s * 256 + l4] = acc[s];
    __syncthreads();

    // fixed-order cross-wave reduce; thread owns d-slice tid*4
    int d4 = tid * 4;
    float4 r0 = *(const float4*)&redbuf[0][d4];
    float4 r1 = *(const float4*)&redbuf[1][d4];
    float4 r2 = *(const float4*)&redbuf[2][d4];
    float4 r3 = *(const float4*)&redbuf[3][d4];
    float4 R;
    R.x = (r0.x + r1.x) + (r2.x + r3.x);
    R.y = (r0.y + r1.y) + (r2.y + r3.y);
    R.z = (r0.z + r1.z) + (r2.z + r3.z);
    R.w = (r0.w + r1.w) + (r2.w + r3.w);
    *(float4*)&partial[((size_t)(b * NCH + x)) * DD + d4] = R;
    if (tid == 0)
        psum[b * NCH + x] = (esums[0] + esums[1]) + (esums[2] + esums[3]);
}

// ---------------------------------------------------------------------------
// blocks 0..255 : ctx[b,d] = (sum live chunks partial)/S   (b=bx>>3, 128-d slice)
// blocks 256..319: attn[b,t] = (t<len) ? escore/S : 0
__global__ void __launch_bounds__(256) finalize_kernel(
        const float* __restrict__ partial, const float* __restrict__ escore,
        const float* __restrict__ psum, const int* __restrict__ seq_lens,
        float* __restrict__ ctx, float* __restrict__ attn) {
    __shared__ float red[NCH];
    __shared__ float part[256];
    int bx = blockIdx.x, tid = threadIdx.x;
    int b  = (bx < 256) ? (bx >> 3) : ((bx - 256) >> 1);
    int len = seq_lens[b];
    int nch = (len + CHK - 1) / CHK;

    if (tid < NCH) red[tid] = (tid < nch) ? psum[b * NCH + tid] : 0.0f;
    __syncthreads();
    #pragma unroll
    for (int off = NCH / 2; off; off >>= 1) {
        if (tid < off) red[tid] += red[tid + off];
        __syncthreads();
    }
    float Sinv = 1.0f / red[0];

    if (bx < 256) {
        int e = tid & 127, g = tid >> 7;
        int d = (bx & 7) * 128 + e;
        const float* pb = partial + (size_t)b * NCH * DD + d;
        int cbeg = g * 32, cend = min(nch, cbeg + 32);
        float a0 = 0.0f, a1 = 0.0f, a2 = 0.0f, a3 = 0.0f;
        int c = cbeg;
        for (; c + 3 < cend; c += 4) {
            a0 += pb[(size_t)(c + 0) * DD];
            a1 += pb[(size_t)(c + 1) * DD];
            a2 += pb[(size_t)(c + 2) * DD];
            a3 += pb[(size_t)(c + 3) * DD];
        }
        for (; c < cend; ++c) a0 += pb[(size_t)c * DD];
        part[tid] = (a0 + a1) + (a2 + a3);
        __syncthreads();
        if (g == 0) ctx[(size_t)b * DD + d] = (part[tid] + part[tid + 128]) * Sinv;
    } else {
        int idx = (bx - 256) * 1024 + tid * 4;    // 64 blocks x 1024 elems
        int t   = idx & (TT - 1);
        float4 e4 = *(const float4*)&escore[(size_t)b * TT + t];
        float4 o;
        o.x = (t + 0 < len) ? e4.x * Sinv : 0.0f;
        o.y = (t + 1 < len) ? e4.y * Sinv : 0.0f;
        o.z = (t + 2 < len) ? e4.z * Sinv : 0.0f;
        o.w = (t + 3 < len) ? e4.w * Sinv : 0.0f;
        *(float4*)&attn[(size_t)b * TT + t] = o;
    }
}

// ---------------------------------------------------------------------------
extern "C" void kernel_launch(void* const* d_in, const int* in_sizes, int n_in,
                              void* d_out, int out_size, void* d_ws, size_t ws_size,
                              hipStream_t stream) {
    const float* hidden   = (const float*)d_in[0];
    const float* key      = (const float*)d_in[1];
    const float* value    = (const float*)d_in[2];
    const int*   seq_lens = (const int*)  d_in[3];
    const float* Wq       = (const float*)d_in[4];
    const float* bq       = (const float*)d_in[5];
    const float* W1       = (const float*)d_in[6];
    const float* b1       = (const float*)d_in[7];
    const float* W2       = (const float*)d_in[8];
    const float* b2       = (const float*)d_in[9];

    float* out  = (float*)d_out;
    float* ctx  = out;                 // [32*1024]
    float* attn = out + BB * DD;       // [32*2048]

    float* ws      = (float*)d_ws;
    float* w       = ws;                               // 1024
    float* cb      = ws + 1024;                        // cb[0], cb[1] (padded)
    float* query   = ws + 2048;                        // 32768
    float* qpart   = query + BB * DD;                  // 64*32*1024 = 2 M floats
    float* escore  = qpart + (size_t)QKS * BB * DD;    // 65536
    float* psum    = escore + BB * TT;                 // 32*64 = 2048
    float* partial = psum + BB * NCH;                  // 32*64*1024 = 8 MB

    prep_query_kernel<<<dim3(5 + 4 * QKS), dim3(256), 0, stream>>>(
        hidden, Wq, W1, b1, W2, b2, w, cb, qpart);
    qreduce_kernel<<<dim3(BB * DD / 128 + 1), dim3(256), 0, stream>>>(
        qpart, bq, w, cb, query);
    score_ctx_kernel<<<dim3(BB * NCH), dim3(256), 0, stream>>>(
        key, value, query, w, cb, seq_lens, escore, psum, partial);
    finalize_kernel<<<dim3(320), dim3(256), 0, stream>>>(
        partial, escore, psum, seq_lens, ctx, attn);
}

// Round 13
// 82.198 us; speedup vs baseline: 1.5232x; 1.5232x over previous
//
#include <hip/hip_runtime.h>
#include <math.h>

#define BB 32
#define TT 2048
#define DD 1024   // HID == OUT == DV == 1024
#define HF 512    // OUT/2

#define QKS 64            // k-split chunks for query projection
#define QCH (DD / QKS)    // 16 h per chunk

#define CHK 32            // t-rows per fused score+context chunk
#define NCH (TT / CHK)    // 64 chunks per batch row

#define KSC 2.88539008177792681f   // 2*log2(e): exp(2x) == exp2(KSC*x)

#if __has_builtin(__builtin_amdgcn_exp2f)
#define EXP2F(x) __builtin_amdgcn_exp2f(x)
#else
#define EXP2F(x) exp2f(x)
#endif

// ---------------------------------------------------------------------------
// blocks 0..3: w[d]=sum_j W1[d,j]*W2[j]; block 4: cbias; blocks 5..260: qpart
__global__ void __launch_bounds__(256) prep_query_kernel(
        const float* __restrict__ hidden, const float* __restrict__ Wq,
        const float* __restrict__ W1, const float* __restrict__ b1,
        const float* __restrict__ W2, const float* __restrict__ b2,
        float* __restrict__ w, float* __restrict__ cbias,
        float* __restrict__ qpart) {
    __shared__ float smem[BB * QCH];   // 512 floats
    int bx  = blockIdx.x;
    int tid = threadIdx.x;

    if (bx < 4) {                                   // ---- w = W1 @ W2
        int d = bx * 256 + tid;
        const float* row = W1 + (size_t)d * HF;
        float acc = 0.0f;
        #pragma unroll 8
        for (int j = 0; j < HF; j += 4) {
            float4 a = *(const float4*)(row + j);
            float4 b = *(const float4*)(W2 + j);
            acc += a.x * b.x + a.y * b.y + a.z * b.z + a.w * b.w;
        }
        w[d] = acc;
        return;
    }
    if (bx == 4) {                                  // ---- cbias
        __shared__ float red[256];
        float s = b1[tid] * W2[tid] + b1[tid + 256] * W2[tid + 256];
        red[tid] = s;
        __syncthreads();
        for (int off = 128; off; off >>= 1) {
            if (tid < off) red[tid] += red[tid + off];
            __syncthreads();
        }
        if (tid == 0) cbias[0] = red[0] + b2[0];
        return;
    }
    // ---- query partial: idx -> (otile, ks)
    int idx = bx - 5, otile = idx & 3, ks = idx >> 2;
    int o = otile * 256 + tid, h0 = ks * QCH;
    if (tid < 128) {   // 128 threads x float4 = 512 floats = 32 rows x 16 h
        int r = tid >> 2, c4 = (tid & 3) << 2;
        *(float4*)&smem[r * QCH + c4] = *(const float4*)&hidden[(size_t)r * DD + h0 + c4];
    }
    __syncthreads();

    float wv[QCH];
    #pragma unroll
    for (int h = 0; h < QCH; ++h)
        wv[h] = Wq[(size_t)(h0 + h) * DD + o];

    float acc[BB];
    #pragma unroll
    for (int b = 0; b < BB; ++b) acc[b] = 0.0f;
    #pragma unroll
    for (int h = 0; h < QCH; ++h) {
        #pragma unroll
        for (int b = 0; b < BB; ++b)
            acc[b] = fmaf(smem[b * QCH + h], wv[h], acc[b]);
    }
    #pragma unroll
    for (int b = 0; b < BB; ++b)
        qpart[((size_t)ks * BB + b) * DD + o] = acc[b];
}

// ---------------------------------------------------------------------------
// blocks 0..255: query[b,o] = bq[o] + sum_ks qpart[ks][b][o]
// block 256    : cb[1] = cb[0] + sum_d w[d]   (bias for the sigma-form score)
__global__ void __launch_bounds__(256) qreduce_kernel(
        const float* __restrict__ qpart, const float* __restrict__ bq,
        const float* __restrict__ w, float* __restrict__ cb,
        float* __restrict__ query) {
    __shared__ float part[256];
    int bx = blockIdx.x, tid = threadIdx.x;
    if (bx == 256) {                                // ---- Wsum role
        float s = w[tid] + w[tid + 256] + w[tid + 512] + w[tid + 768];
        part[tid] = s;
        __syncthreads();
        for (int off = 128; off; off >>= 1) {
            if (tid < off) part[tid] += part[tid + off];
            __syncthreads();
        }
        if (tid == 0) cb[1] = cb[0] + part[0];
        return;
    }
    int e = tid & 127, g = tid >> 7;
    int i = bx * 128 + e;
    int ks0 = g * (QKS / 2);
    float a0 = 0.0f, a1 = 0.0f, a2 = 0.0f, a3 = 0.0f;
    #pragma unroll 8
    for (int k = 0; k < QKS / 2; k += 4) {
        size_t base = (size_t)(ks0 + k) * (BB * DD) + i;
        a0 += qpart[base];
        a1 += qpart[base + (size_t)(BB * DD)];
        a2 += qpart[base + 2 * (size_t)(BB * DD)];
        a3 += qpart[base + 3 * (size_t)(BB * DD)];
    }
    part[tid] = (a0 + a1) + (a2 + a3);
    __syncthreads();
    if (g == 0) query[i] = bq[i & (DD - 1)] + part[tid] + part[tid + 128];
}

// ---------------------------------------------------------------------------
// Fused scores + unnormalized context partials for one 32-row chunk.
// Residency-aware decode: a CU's co-resident blocks are n, n+256, ... (8-XCD
// round-robin then 32 CUs/XCD). b must vary across BOTH stride-256 and
// contiguous resident sets -> bijective bit-mix:
//   hi=n[10:8]; b=((n[2:0]^hi)<<2)|n[7:6]; x=n[5:3]|(hi<<3)
// (stride-256 set: 8 distinct b AND 8 distinct x; contiguous set: 8 distinct b)
__global__ void __launch_bounds__(256, 6) score_ctx_kernel(
        const float* __restrict__ key, const float* __restrict__ value,
        const float* __restrict__ query, const float* __restrict__ w,
        const float* __restrict__ cb, const int* __restrict__ seq_lens,
        float* __restrict__ escore, float* __restrict__ psum,
        float* __restrict__ partial) {
    int n    = blockIdx.x;                    // 0..2047
    int hi   = n >> 8;                        // 3 bits
    int b    = (((n & 7) ^ hi) << 2) | ((n >> 6) & 3);
    int x    = ((n >> 3) & 7) | (hi << 3);
    int len  = seq_lens[b];
    int t0   = x * CHK;
    if (t0 >= len) return;

    __shared__ float wsh[DD];
    __shared__ float qsh[DD];
    __shared__ float esm[CHK];
    int tid = threadIdx.x;
    { int i4 = tid * 4;
      float4 w4 = *(const float4*)&w[i4];
      float4 q4 = *(const float4*)&query[(size_t)b * DD + i4];
      float4 ws = {-2.0f * w4.x, -2.0f * w4.y, -2.0f * w4.z, -2.0f * w4.w};
      float4 qs = {KSC * q4.x, KSC * q4.y, KSC * q4.z, KSC * q4.w};
      *(float4*)&wsh[i4] = ws;
      *(float4*)&qsh[i4] = qs; }
    __syncthreads();

    int wave = tid >> 6, lane = tid & 63;
    float c2 = cb[1];                 // cbias + sum_d w
    const float* kb0 = key + (size_t)b * TT * DD;

    // ---- scores: wave handles rows j*4 + wave, 2-deep register pipeline
    float4 kreg[2][4];
    {
        const float* kr = kb0 + (size_t)(t0 + wave) * DD;
        #pragma unroll
        for (int s = 0; s < 4; ++s)
            kreg[0][s] = *(const float4*)(kr + s * 256 + lane * 4);
    }
    #pragma unroll
    for (int j = 0; j < 8; ++j) {
        if (j < 7) {
            const float* kr = kb0 + (size_t)(t0 + (j + 1) * 4 + wave) * DD;
            #pragma unroll
            for (int s = 0; s < 4; ++s)
                kreg[(j + 1) & 1][s] = *(const float4*)(kr + s * 256 + lane * 4);
        }
        float acc = 0.0f;
        #pragma unroll
        for (int s = 0; s < 4; ++s) {
            int d = s * 256 + lane * 4;
            float4 kv = kreg[j & 1][s];
            float4 qv = *(const float4*)&qsh[d];
            float4 wv = *(const float4*)&wsh[d];
            float r0 = __builtin_amdgcn_rcpf(EXP2F(fmaf(kv.x, KSC, qv.x)) + 1.0f);
            float r1 = __builtin_amdgcn_rcpf(EXP2F(fmaf(kv.y, KSC, qv.y)) + 1.0f);
            float r2 = __builtin_amdgcn_rcpf(EXP2F(fmaf(kv.z, KSC, qv.z)) + 1.0f);
            float r3 = __builtin_amdgcn_rcpf(EXP2F(fmaf(kv.w, KSC, qv.w)) + 1.0f);
            acc = fmaf(wv.x, r0, acc);
            acc = fmaf(wv.y, r1, acc);
            acc = fmaf(wv.z, r2, acc);
            acc = fmaf(wv.w, r3, acc);
        }
        #pragma unroll
        for (int off = 32; off; off >>= 1) acc += __shfl_down(acc, off);
        if (lane == 0) {
            int t = t0 + j * 4 + wave;
            esm[j * 4 + wave] = (t < len) ? __expf(acc + c2) : 0.0f;
        }
    }
    __syncthreads();

    // ---- escore + psum (fixed order, deterministic)
    if (tid < CHK) escore[(size_t)b * TT + t0 + tid] = esm[tid];
    if (tid == 0) {
        float s = 0.0f;
        #pragma unroll
        for (int i = 0; i < CHK; ++i) s += esm[i];
        psum[b * NCH + x] = s;
    }

    // ---- PV: 4 accumulator chains, branch-free over all 32 rows
    int d4 = tid * 4;
    const float* vbase = value + (size_t)b * TT * DD + d4;
    float4 A0 = {0.0f, 0.0f, 0.0f, 0.0f};
    float4 A1 = A0, A2 = A0, A3 = A0;
    #pragma unroll 2
    for (int tt = 0; tt < CHK; tt += 4) {
        float e0 = esm[tt], e1 = esm[tt + 1], e2 = esm[tt + 2], e3 = esm[tt + 3];
        float4 v0 = *(const float4*)(vbase + (size_t)(t0 + tt    ) * DD);
        float4 v1 = *(const float4*)(vbase + (size_t)(t0 + tt + 1) * DD);
        float4 v2 = *(const float4*)(vbase + (size_t)(t0 + tt + 2) * DD);
        float4 v3 = *(const float4*)(vbase + (size_t)(t0 + tt + 3) * DD);
        A0.x = fmaf(e0, v0.x, A0.x); A0.y = fmaf(e0, v0.y, A0.y);
        A0.z = fmaf(e0, v0.z, A0.z); A0.w = fmaf(e0, v0.w, A0.w);
        A1.x = fmaf(e1, v1.x, A1.x); A1.y = fmaf(e1, v1.y, A1.y);
        A1.z = fmaf(e1, v1.z, A1.z); A1.w = fmaf(e1, v1.w, A1.w);
        A2.x = fmaf(e2, v2.x, A2.x); A2.y = fmaf(e2, v2.y, A2.y);
        A2.z = fmaf(e2, v2.z, A2.z); A2.w = fmaf(e2, v2.w, A2.w);
        A3.x = fmaf(e3, v3.x, A3.x); A3.y = fmaf(e3, v3.y, A3.y);
        A3.z = fmaf(e3, v3.z, A3.z); A3.w = fmaf(e3, v3.w, A3.w);
    }
    float4 R;
    R.x = (A0.x + A1.x) + (A2.x + A3.x);
    R.y = (A0.y + A1.y) + (A2.y + A3.y);
    R.z = (A0.z + A1.z) + (A2.z + A3.z);
    R.w = (A0.w + A1.w) + (A2.w + A3.w);
    *(float4*)&partial[((size_t)(b * NCH + x)) * DD + d4] = R;
}

// ---------------------------------------------------------------------------
// blocks 0..255 : ctx[b,d] = (sum live chunks partial)/S   (b=bx>>3, 128-d slice)
// blocks 256..319: attn[b,t] = (t<len) ? escore/S : 0
__global__ void __launch_bounds__(256) finalize_kernel(
        const float* __restrict__ partial, const float* __restrict__ escore,
        const float* __restrict__ psum, const int* __restrict__ seq_lens,
        float* __restrict__ ctx, float* __restrict__ attn) {
    __shared__ float red[NCH];
    __shared__ float part[256];
    int bx = blockIdx.x, tid = threadIdx.x;
    int b  = (bx < 256) ? (bx >> 3) : ((bx - 256) >> 1);
    int len = seq_lens[b];
    int nch = (len + CHK - 1) / CHK;

    if (tid < NCH) red[tid] = (tid < nch) ? psum[b * NCH + tid] : 0.0f;
    __syncthreads();
    #pragma unroll
    for (int off = NCH / 2; off; off >>= 1) {
        if (tid < off) red[tid] += red[tid + off];
        __syncthreads();
    }
    float Sinv = 1.0f / red[0];

    if (bx < 256) {
        int e = tid & 127, g = tid >> 7;
        int d = (bx & 7) * 128 + e;
        const float* pb = partial + (size_t)b * NCH * DD + d;
        int cbeg = g * 32, cend = min(nch, cbeg + 32);
        float a0 = 0.0f, a1 = 0.0f, a2 = 0.0f, a3 = 0.0f;
        int c = cbeg;
        for (; c + 3 < cend; c += 4) {
            a0 += pb[(size_t)(c + 0) * DD];
            a1 += pb[(size_t)(c + 1) * DD];
            a2 += pb[(size_t)(c + 2) * DD];
            a3 += pb[(size_t)(c + 3) * DD];
        }
        for (; c < cend; ++c) a0 += pb[(size_t)c * DD];
        part[tid] = (a0 + a1) + (a2 + a3);
        __syncthreads();
        if (g == 0) ctx[(size_t)b * DD + d] = (part[tid] + part[tid + 128]) * Sinv;
    } else {
        int idx = (bx - 256) * 1024 + tid * 4;    // 64 blocks x 1024 elems
        int t   = idx & (TT - 1);
        float4 e4 = *(const float4*)&escore[(size_t)b * TT + t];
        float4 o;
        o.x = (t + 0 < len) ? e4.x * Sinv : 0.0f;
        o.y = (t + 1 < len) ? e4.y * Sinv : 0.0f;
        o.z = (t + 2 < len) ? e4.z * Sinv : 0.0f;
        o.w = (t + 3 < len) ? e4.w * Sinv : 0.0f;
        *(float4*)&attn[(size_t)b * TT + t] = o;
    }
}

// ---------------------------------------------------------------------------
extern "C" void kernel_launch(void* const* d_in, const int* in_sizes, int n_in,
                              void* d_out, int out_size, void* d_ws, size_t ws_size,
                              hipStream_t stream) {
    const float* hidden   = (const float*)d_in[0];
    const float* key      = (const float*)d_in[1];
    const float* value    = (const float*)d_in[2];
    const int*   seq_lens = (const int*)  d_in[3];
    const float* Wq       = (const float*)d_in[4];
    const float* bq       = (const float*)d_in[5];
    const float* W1       = (const float*)d_in[6];
    const float* b1       = (const float*)d_in[7];
    const float* W2       = (const float*)d_in[8];
    const float* b2       = (const float*)d_in[9];

    float* out  = (float*)d_out;
    float* ctx  = out;                 // [32*1024]
    float* attn = out + BB * DD;       // [32*2048]

    float* ws      = (float*)d_ws;
    float* w       = ws;                               // 1024
    float* cb      = ws + 1024;                        // cb[0], cb[1] (padded)
    float* query   = ws + 2048;                        // 32768
    float* qpart   = query + BB * DD;                  // 64*32*1024 = 2 M floats
    float* escore  = qpart + (size_t)QKS * BB * DD;    // 65536
    float* psum    = escore + BB * TT;                 // 32*64 = 2048
    float* partial = psum + BB * NCH;                  // 32*64*1024 = 8 MB

    prep_query_kernel<<<dim3(5 + 4 * QKS), dim3(256), 0, stream>>>(
        hidden, Wq, W1, b1, W2, b2, w, cb, qpart);
    qreduce_kernel<<<dim3(BB * DD / 128 + 1), dim3(256), 0, stream>>>(
        qpart, bq, w, cb, query);
    score_ctx_kernel<<<dim3(BB * NCH), dim3(256), 0, stream>>>(
        key, value, query, w, cb, seq_lens, escore, psum, partial);
    finalize_kernel<<<dim3(320), dim3(256), 0, stream>>>(
        partial, escore, psum, seq_lens, ctx, attn);
}

// Round 14
// 81.028 us; speedup vs baseline: 1.5452x; 1.0144x over previous
//
#include <hip/hip_runtime.h>
#include <math.h>

#define BB 32
#define TT 2048
#define DD 1024   // HID == OUT == DV == 1024
#define HF 512    // OUT/2

#define QKS 64            // k-split chunks for query projection
#define QCH (DD / QKS)    // 16 h per chunk

#define CHK 16            // t-rows per fused score+context chunk
#define NCH (TT / CHK)    // 128 chunks per batch row

#define KSC 2.88539008177792681f   // 2*log2(e): exp(2x) == exp2(KSC*x)

#if __has_builtin(__builtin_amdgcn_exp2f)
#define EXP2F(x) __builtin_amdgcn_exp2f(x)
#else
#define EXP2F(x) exp2f(x)
#endif

// ---------------------------------------------------------------------------
// blocks 0..3: w[d]=sum_j W1[d,j]*W2[j]; block 4: cbias; blocks 5..260: qpart
__global__ void __launch_bounds__(256) prep_query_kernel(
        const float* __restrict__ hidden, const float* __restrict__ Wq,
        const float* __restrict__ W1, const float* __restrict__ b1,
        const float* __restrict__ W2, const float* __restrict__ b2,
        float* __restrict__ w, float* __restrict__ cbias,
        float* __restrict__ qpart) {
    __shared__ float smem[BB * QCH];   // 512 floats
    int bx  = blockIdx.x;
    int tid = threadIdx.x;

    if (bx < 4) {                                   // ---- w = W1 @ W2
        int d = bx * 256 + tid;
        const float* row = W1 + (size_t)d * HF;
        float acc = 0.0f;
        #pragma unroll 8
        for (int j = 0; j < HF; j += 4) {
            float4 a = *(const float4*)(row + j);
            float4 b = *(const float4*)(W2 + j);
            acc += a.x * b.x + a.y * b.y + a.z * b.z + a.w * b.w;
        }
        w[d] = acc;
        return;
    }
    if (bx == 4) {                                  // ---- cbias
        __shared__ float red[256];
        float s = b1[tid] * W2[tid] + b1[tid + 256] * W2[tid + 256];
        red[tid] = s;
        __syncthreads();
        for (int off = 128; off; off >>= 1) {
            if (tid < off) red[tid] += red[tid + off];
            __syncthreads();
        }
        if (tid == 0) cbias[0] = red[0] + b2[0];
        return;
    }
    // ---- query partial: idx -> (otile, ks)
    int idx = bx - 5, otile = idx & 3, ks = idx >> 2;
    int o = otile * 256 + tid, h0 = ks * QCH;
    if (tid < 128) {   // 128 threads x float4 = 512 floats = 32 rows x 16 h
        int r = tid >> 2, c4 = (tid & 3) << 2;
        *(float4*)&smem[r * QCH + c4] = *(const float4*)&hidden[(size_t)r * DD + h0 + c4];
    }
    __syncthreads();

    float wv[QCH];
    #pragma unroll
    for (int h = 0; h < QCH; ++h)
        wv[h] = Wq[(size_t)(h0 + h) * DD + o];

    float acc[BB];
    #pragma unroll
    for (int b = 0; b < BB; ++b) acc[b] = 0.0f;
    #pragma unroll
    for (int h = 0; h < QCH; ++h) {
        #pragma unroll
        for (int b = 0; b < BB; ++b)
            acc[b] = fmaf(smem[b * QCH + h], wv[h], acc[b]);
    }
    #pragma unroll
    for (int b = 0; b < BB; ++b)
        qpart[((size_t)ks * BB + b) * DD + o] = acc[b];
}

// ---------------------------------------------------------------------------
// blocks 0..255: query[b,o] = bq[o] + sum_ks qpart[ks][b][o]
// block 256    : cb[1] = cb[0] + sum_d w[d]   (bias for the sigma-form score)
__global__ void __launch_bounds__(256) qreduce_kernel(
        const float* __restrict__ qpart, const float* __restrict__ bq,
        const float* __restrict__ w, float* __restrict__ cb,
        float* __restrict__ query) {
    __shared__ float part[256];
    int bx = blockIdx.x, tid = threadIdx.x;
    if (bx == 256) {                                // ---- Wsum role
        float s = w[tid] + w[tid + 256] + w[tid + 512] + w[tid + 768];
        part[tid] = s;
        __syncthreads();
        for (int off = 128; off; off >>= 1) {
            if (tid < off) part[tid] += part[tid + off];
            __syncthreads();
        }
        if (tid == 0) cb[1] = cb[0] + part[0];
        return;
    }
    int e = tid & 127, g = tid >> 7;
    int i = bx * 128 + e;
    int ks0 = g * (QKS / 2);
    float a0 = 0.0f, a1 = 0.0f, a2 = 0.0f, a3 = 0.0f;
    #pragma unroll 8
    for (int k = 0; k < QKS / 2; k += 4) {
        size_t base = (size_t)(ks0 + k) * (BB * DD) + i;
        a0 += qpart[base];
        a1 += qpart[base + (size_t)(BB * DD)];
        a2 += qpart[base + 2 * (size_t)(BB * DD)];
        a3 += qpart[base + 3 * (size_t)(BB * DD)];
    }
    part[tid] = (a0 + a1) + (a2 + a3);
    __syncthreads();
    if (g == 0) query[i] = bq[i & (DD - 1)] + part[tid] + part[tid + 128];
}

// ---------------------------------------------------------------------------
// Fused scores + unnormalized context partials for one 16-row chunk.
// 4096 blocks = 2.7x oversubscribed (backfill balances len-dependent exits).
// Residency decode (stride-256 AND contiguous resident sets get b-diversity):
//   hi=n[11:8]; b=((n[2:0]^hi[2:0])<<2)|n[7:6]; x=n[5:3]|(hi<<3)   (bijective)
__global__ void __launch_bounds__(256, 6) score_ctx_kernel(
        const float* __restrict__ key, const float* __restrict__ value,
        const float* __restrict__ query, const float* __restrict__ w,
        const float* __restrict__ cb, const int* __restrict__ seq_lens,
        float* __restrict__ escore, float* __restrict__ psum,
        float* __restrict__ partial) {
    int n    = blockIdx.x;                    // 0..4095
    int hi   = n >> 8;                        // 4 bits
    int b    = (((n & 7) ^ (hi & 7)) << 2) | ((n >> 6) & 3);
    int x    = ((n >> 3) & 7) | (hi << 3);    // 0..127
    int len  = seq_lens[b];
    int t0   = x * CHK;
    if (t0 >= len) return;

    __shared__ float wsh[DD];
    __shared__ float qsh[DD];
    __shared__ float esm[CHK];
    int tid = threadIdx.x;
    { int i4 = tid * 4;
      float4 w4 = *(const float4*)&w[i4];
      float4 q4 = *(const float4*)&query[(size_t)b * DD + i4];
      float4 ws = {-2.0f * w4.x, -2.0f * w4.y, -2.0f * w4.z, -2.0f * w4.w};
      float4 qs = {KSC * q4.x, KSC * q4.y, KSC * q4.z, KSC * q4.w};
      *(float4*)&wsh[i4] = ws;
      *(float4*)&qsh[i4] = qs; }
    __syncthreads();

    int wave = tid >> 6, lane = tid & 63;
    float c2 = cb[1];                 // cbias + sum_d w
    const float* kb0 = key + (size_t)b * TT * DD;

    // ---- scores: wave handles rows j*4 + wave, 2-deep register pipeline
    float4 kreg[2][4];
    {
        const float* kr = kb0 + (size_t)(t0 + wave) * DD;
        #pragma unroll
        for (int s = 0; s < 4; ++s)
            kreg[0][s] = *(const float4*)(kr + s * 256 + lane * 4);
    }
    #pragma unroll
    for (int j = 0; j < CHK / 4; ++j) {
        if (j < CHK / 4 - 1) {
            const float* kr = kb0 + (size_t)(t0 + (j + 1) * 4 + wave) * DD;
            #pragma unroll
            for (int s = 0; s < 4; ++s)
                kreg[(j + 1) & 1][s] = *(const float4*)(kr + s * 256 + lane * 4);
        }
        float acc = 0.0f;
        #pragma unroll
        for (int s = 0; s < 4; ++s) {
            int d = s * 256 + lane * 4;
            float4 kv = kreg[j & 1][s];
            float4 qv = *(const float4*)&qsh[d];
            float4 wv = *(const float4*)&wsh[d];
            float r0 = __builtin_amdgcn_rcpf(EXP2F(fmaf(kv.x, KSC, qv.x)) + 1.0f);
            float r1 = __builtin_amdgcn_rcpf(EXP2F(fmaf(kv.y, KSC, qv.y)) + 1.0f);
            float r2 = __builtin_amdgcn_rcpf(EXP2F(fmaf(kv.z, KSC, qv.z)) + 1.0f);
            float r3 = __builtin_amdgcn_rcpf(EXP2F(fmaf(kv.w, KSC, qv.w)) + 1.0f);
            acc = fmaf(wv.x, r0, acc);
            acc = fmaf(wv.y, r1, acc);
            acc = fmaf(wv.z, r2, acc);
            acc = fmaf(wv.w, r3, acc);
        }
        #pragma unroll
        for (int off = 32; off; off >>= 1) acc += __shfl_down(acc, off);
        if (lane == 0) {
            int t = t0 + j * 4 + wave;
            esm[j * 4 + wave] = (t < len) ? __expf(acc + c2) : 0.0f;
        }
    }
    __syncthreads();

    // ---- escore + psum (fixed order, deterministic)
    if (tid < CHK) escore[(size_t)b * TT + t0 + tid] = esm[tid];
    if (tid == 0) {
        float s = 0.0f;
        #pragma unroll
        for (int i = 0; i < CHK; ++i) s += esm[i];
        psum[b * NCH + x] = s;
    }

    // ---- PV: 4 accumulator chains, branch-free over all 16 rows
    int d4 = tid * 4;
    const float* vbase = value + (size_t)b * TT * DD + d4;
    float4 A0 = {0.0f, 0.0f, 0.0f, 0.0f};
    float4 A1 = A0, A2 = A0, A3 = A0;
    #pragma unroll 2
    for (int tt = 0; tt < CHK; tt += 4) {
        float e0 = esm[tt], e1 = esm[tt + 1], e2 = esm[tt + 2], e3 = esm[tt + 3];
        float4 v0 = *(const float4*)(vbase + (size_t)(t0 + tt    ) * DD);
        float4 v1 = *(const float4*)(vbase + (size_t)(t0 + tt + 1) * DD);
        float4 v2 = *(const float4*)(vbase + (size_t)(t0 + tt + 2) * DD);
        float4 v3 = *(const float4*)(vbase + (size_t)(t0 + tt + 3) * DD);
        A0.x = fmaf(e0, v0.x, A0.x); A0.y = fmaf(e0, v0.y, A0.y);
        A0.z = fmaf(e0, v0.z, A0.z); A0.w = fmaf(e0, v0.w, A0.w);
        A1.x = fmaf(e1, v1.x, A1.x); A1.y = fmaf(e1, v1.y, A1.y);
        A1.z = fmaf(e1, v1.z, A1.z); A1.w = fmaf(e1, v1.w, A1.w);
        A2.x = fmaf(e2, v2.x, A2.x); A2.y = fmaf(e2, v2.y, A2.y);
        A2.z = fmaf(e2, v2.z, A2.z); A2.w = fmaf(e2, v2.w, A2.w);
        A3.x = fmaf(e3, v3.x, A3.x); A3.y = fmaf(e3, v3.y, A3.y);
        A3.z = fmaf(e3, v3.z, A3.z); A3.w = fmaf(e3, v3.w, A3.w);
    }
    float4 R;
    R.x = (A0.x + A1.x) + (A2.x + A3.x);
    R.y = (A0.y + A1.y) + (A2.y + A3.y);
    R.z = (A0.z + A1.z) + (A2.z + A3.z);
    R.w = (A0.w + A1.w) + (A2.w + A3.w);
    *(float4*)&partial[((size_t)(b * NCH + x)) * DD + d4] = R;
}

// ---------------------------------------------------------------------------
// blocks 0..255 : ctx[b,d] = (sum live chunks partial)/S   (b=bx>>3, 128-d slice)
// blocks 256..319: attn[b,t] = (t<len) ? escore/S : 0
__global__ void __launch_bounds__(256) finalize_kernel(
        const float* __restrict__ partial, const float* __restrict__ escore,
        const float* __restrict__ psum, const int* __restrict__ seq_lens,
        float* __restrict__ ctx, float* __restrict__ attn) {
    __shared__ float red[NCH];
    __shared__ float part[256];
    int bx = blockIdx.x, tid = threadIdx.x;
    int b  = (bx < 256) ? (bx >> 3) : ((bx - 256) >> 1);
    int len = seq_lens[b];
    int nch = (len + CHK - 1) / CHK;

    if (tid < NCH) red[tid] = (tid < nch) ? psum[b * NCH + tid] : 0.0f;
    __syncthreads();
    #pragma unroll
    for (int off = NCH / 2; off; off >>= 1) {
        if (tid < off) red[tid] += red[tid + off];
        __syncthreads();
    }
    float Sinv = 1.0f / red[0];

    if (bx < 256) {
        int e = tid & 127, g = tid >> 7;
        int d = (bx & 7) * 128 + e;
        const float* pb = partial + (size_t)b * NCH * DD + d;
        int cbeg = g * (NCH / 2), cend = min(nch, cbeg + NCH / 2);
        float a0 = 0.0f, a1 = 0.0f, a2 = 0.0f, a3 = 0.0f;
        int c = cbeg;
        for (; c + 3 < cend; c += 4) {
            a0 += pb[(size_t)(c + 0) * DD];
            a1 += pb[(size_t)(c + 1) * DD];
            a2 += pb[(size_t)(c + 2) * DD];
            a3 += pb[(size_t)(c + 3) * DD];
        }
        for (; c < cend; ++c) a0 += pb[(size_t)c * DD];
        part[tid] = (a0 + a1) + (a2 + a3);
        __syncthreads();
        if (g == 0) ctx[(size_t)b * DD + d] = (part[tid] + part[tid + 128]) * Sinv;
    } else {
        int idx = (bx - 256) * 1024 + tid * 4;    // 64 blocks x 1024 elems
        int t   = idx & (TT - 1);
        float4 e4 = *(const float4*)&escore[(size_t)b * TT + t];
        float4 o;
        o.x = (t + 0 < len) ? e4.x * Sinv : 0.0f;
        o.y = (t + 1 < len) ? e4.y * Sinv : 0.0f;
        o.z = (t + 2 < len) ? e4.z * Sinv : 0.0f;
        o.w = (t + 3 < len) ? e4.w * Sinv : 0.0f;
        *(float4*)&attn[(size_t)b * TT + t] = o;
    }
}

// ---------------------------------------------------------------------------
extern "C" void kernel_launch(void* const* d_in, const int* in_sizes, int n_in,
                              void* d_out, int out_size, void* d_ws, size_t ws_size,
                              hipStream_t stream) {
    const float* hidden   = (const float*)d_in[0];
    const float* key      = (const float*)d_in[1];
    const float* value    = (const float*)d_in[2];
    const int*   seq_lens = (const int*)  d_in[3];
    const float* Wq       = (const float*)d_in[4];
    const float* bq       = (const float*)d_in[5];
    const float* W1       = (const float*)d_in[6];
    const float* b1       = (const float*)d_in[7];
    const float* W2       = (const float*)d_in[8];
    const float* b2       = (const float*)d_in[9];

    float* out  = (float*)d_out;
    float* ctx  = out;                 // [32*1024]
    float* attn = out + BB * DD;       // [32*2048]

    float* ws      = (float*)d_ws;
    float* w       = ws;                               // 1024
    float* cb      = ws + 1024;                        // cb[0], cb[1] (padded)
    float* query   = ws + 2048;                        // 32768
    float* qpart   = query + BB * DD;                  // 64*32*1024 = 2 M floats
    float* escore  = qpart + (size_t)QKS * BB * DD;    // 65536
    float* psum    = escore + BB * TT;                 // 32*128 = 4096
    float* partial = psum + BB * NCH;                  // 32*128*1024 = 16 MB

    prep_query_kernel<<<dim3(5 + 4 * QKS), dim3(256), 0, stream>>>(
        hidden, Wq, W1, b1, W2, b2, w, cb, qpart);
    qreduce_kernel<<<dim3(BB * DD / 128 + 1), dim3(256), 0, stream>>>(
        qpart, bq, w, cb, query);
    score_ctx_kernel<<<dim3(BB * NCH), dim3(256), 0, stream>>>(
        key, value, query, w, cb, seq_lens, escore, psum, partial);
    finalize_kernel<<<dim3(320), dim3(256), 0, stream>>>(
        partial, escore, psum, seq_lens, ctx, attn);
}